// Round 5
// baseline (161.417 us; speedup 1.0000x reference)
//
#include <hip/hip_runtime.h>
#include <math.h>

// B=2, C=O=256, H=W=64, K=33 offsets (D=4 rings).
//
// Algebra: aff[k,p] = Eg(p)·Ef(p_k) = G(p)·Ft(p_k) + const(p), with
// G = (Wf^T Wg)·Ftε + Wf^T bg; const(p) cancels in softmax.
// Pipeline: mat_M (64 blk, emits Mt[k][m]) -> gemm_G (512 blk, streaming,
// no LDS) -> aff_part (512 blk, windowed b128) -> out_kernel (fused softmax).
typedef __attribute__((ext_vector_type(4))) float f4;

__device__ __forceinline__ int iclamp(int x, int lo, int hi) { return min(max(x, lo), hi); }

// k=0:(0,0); rings s=1..4: (-s,-s),(-s,0),(-s,s),(0,-s),(0,s),(s,-s),(s,0),(s,s)
__device__ constexpr int DXC[33] = {0, -1,-1,-1,0,0,1,1,1, -2,-2,-2,0,0,2,2,2, -3,-3,-3,0,0,3,3,3, -4,-4,-4,0,0,4,4,4};
__device__ constexpr int DYC[33] = {0, -1,0,1,-1,1,-1,0,1, -2,0,2,-2,2,-2,0,2, -3,0,3,-3,3,-3,0,3, -4,0,4,-4,4,-4,0,4};

// ---------------------------------------------------------------------------
// mat_M: Mt[c2][c1] = sum_o Wf[o,c1]*Wg[o,c2]  (transposed for streaming gemm)
//        r[c1]     = sum_o Wf[o,c1]*bg[o]
// grid (8,8) = 64 blocks (32x32 tiles, 2x2 acc).
// ---------------------------------------------------------------------------
__global__ __launch_bounds__(256) void mat_M(
    const float* __restrict__ Wf, const float* __restrict__ Wg,
    const float* __restrict__ bg, float* __restrict__ Mt, float* __restrict__ r)
{
    __shared__ float Sf[32][33], Sg[32][33];
    __shared__ float Rs[32][9];
    const int c1b = blockIdx.x * 32, c2b = blockIdx.y * 32;
    const int tid = threadIdx.x;
    const int tx = tid & 15, ty = tid >> 4;
    float acc[2][2] = {};
    for (int ko = 0; ko < 256; ko += 32) {
        #pragma unroll
        for (int i = 0; i < 4; ++i) {
            int f = i * 256 + tid, o = f >> 5, c = f & 31;
            Sf[o][c] = Wf[(ko + o) * 256 + c1b + c];
            Sg[o][c] = Wg[(ko + o) * 256 + c2b + c];
        }
        __syncthreads();
        #pragma unroll
        for (int o = 0; o < 32; ++o) {
            float f0 = Sf[o][ty * 2], f1 = Sf[o][ty * 2 + 1];
            float g0 = Sg[o][tx * 2], g1 = Sg[o][tx * 2 + 1];
            acc[0][0] += f0 * g0; acc[0][1] += f0 * g1;
            acc[1][0] += f1 * g0; acc[1][1] += f1 * g1;
        }
        __syncthreads();
    }
    #pragma unroll
    for (int i = 0; i < 2; ++i)
        #pragma unroll
        for (int j = 0; j < 2; ++j)
            Mt[(size_t)(c2b + tx * 2 + j) * 256 + c1b + ty * 2 + i] = acc[i][j];

    if (blockIdx.y == 0) {   // block-uniform
        const int c1l = tid & 31, og = tid >> 5;
        float s = 0.f;
        #pragma unroll 8
        for (int o = og * 32; o < og * 32 + 32; ++o)
            s += Wf[o * 256 + c1b + c1l] * bg[o];
        Rs[c1l][og] = s;
        __syncthreads();
        if (tid < 32) {
            float t = 0.f;
            #pragma unroll
            for (int j = 0; j < 8; ++j) t += Rs[tid][j];
            r[c1b + tid] = t;
        }
    }
}

// ---------------------------------------------------------------------------
// gemm_G v3 (streaming, no LDS, no barriers):
// G[b][m][p] = sum_k Mt[k][m]*Ftε[b][k][p] + r[m].
// Grid 512 (bn 0..63, bm 0..3, b 0..1): 64x64 tile, 4m x 4n acc/thread.
// A-frag: 4 distinct f4/wave (L1 broadcast); B-frag: 16 f4 coalesced.
// 2 blocks/CU, 2 waves/SIMD; 2 VMEM + 16 FMA per k.
// ---------------------------------------------------------------------------
__global__ __launch_bounds__(256) void gemm_G(
    const float* __restrict__ Mt, const float* __restrict__ r,
    const float* __restrict__ FtE, float* __restrict__ G)
{
    const int bid = blockIdx.x;
    const int bn = bid & 63, bm = (bid >> 6) & 3, b = bid >> 8;
    const int tid = threadIdx.x;
    const int tn = tid & 15, tm = tid >> 4;
    const int m0g = bm * 64 + tm * 4;
    const int n0g = bn * 64 + tn * 4;
    const float* A = Mt + m0g;                           // + k*256
    const float* X = FtE + (size_t)b * 1048576 + n0g;    // + k*4096

    f4 acc0 = {0.f,0.f,0.f,0.f}, acc1 = acc0, acc2 = acc0, acc3 = acc0;

    #pragma unroll 8
    for (int k = 0; k < 256; ++k) {
        f4 a = *(const f4*)(A + (size_t)k * 256);
        f4 x = *(const f4*)(X + (size_t)k * 4096);
        acc0 += x * a.x;
        acc1 += x * a.y;
        acc2 += x * a.z;
        acc3 += x * a.w;
    }

    float* Gp = G + (size_t)b * 1048576;
    {
        f4 v;
        v = acc0 + r[m0g + 0]; *(f4*)&Gp[(size_t)(m0g + 0) * 4096 + n0g] = v;
        v = acc1 + r[m0g + 1]; *(f4*)&Gp[(size_t)(m0g + 1) * 4096 + n0g] = v;
        v = acc2 + r[m0g + 2]; *(f4*)&Gp[(size_t)(m0g + 2) * 4096 + n0g] = v;
        v = acc3 + r[m0g + 3]; *(f4*)&Gp[(size_t)(m0g + 3) * 4096 + n0g] = v;
    }
}

// ---------------------------------------------------------------------------
// Windowed-register helpers: a 12-wide row window (3 aligned b128 from LDS)
// serves all dy in [-4,4] for 4 consecutive pixels via compile-time indices.
// ---------------------------------------------------------------------------
template<bool LO, bool HI>
__device__ __forceinline__ void ldwin(float* wn, const float* Lb, int rd, int ch, int wq) {
    const float* p = &Lb[(rd * 8 + ch) * 72 + wq * 4];   // aligned: 72%4==0, wq*4
    if constexpr (LO) { f4 v = *(const f4*)p;       wn[0]=v.x; wn[1]=v.y; wn[2]=v.z;  wn[3]=v.w; }
    {                   f4 v = *(const f4*)(p + 4); wn[4]=v.x; wn[5]=v.y; wn[6]=v.z;  wn[7]=v.w; }
    if constexpr (HI) { f4 v = *(const f4*)(p + 8); wn[8]=v.x; wn[9]=v.y; wn[10]=v.z; wn[11]=v.w; }
}

// acc[px] += eg[px] * window[4 + px + DY]   (px = 0..3, all compile-time)
template<int DY>
__device__ __forceinline__ void fmadd4(f4& a, const f4& eg, const float* wn) {
    a.x += eg.x * wn[4 + DY];
    a.y += eg.y * wn[5 + DY];
    a.z += eg.z * wn[6 + DY];
    a.w += eg.w * wn[7 + DY];
}

// ---------------------------------------------------------------------------
// aff_part v3: part[cseg][b][k][p] = sum_{c in cseg's 64} G[c,p]*Ft[c,p+off_k]
// grid (64 h, 2 b, 4 cseg). Threads: wq=tid&15 (4 px), cg=(tid>>4)&3 (ch-pair),
// kq=tid>>6 (wave-uniform k-row split). Staging unchanged (pre-clamped halos).
// Rows (rd = dx+4): rd4 = center (9 k), others 3 k each.
//   kq0: rd 0,1,2   kq1: rd3 + rd4(dy<0)   kq2: rd4(dy>=0) + rd5   kq3: rd 6,7,8
// Partials accumulate over rounds; one final shfl_xor butterfly over cg.
// ---------------------------------------------------------------------------
template<int KQ>
__device__ __forceinline__ void aff_compute(const float* Lb, int wq, int cg, f4* acc)
{
    #pragma unroll
    for (int chi = 0; chi < 2; ++chi) {
        const int ch = cg * 2 + chi;
        f4 eg = *(const f4*)&Lb[(72 + ch) * 72 + 4 + wq * 4];   // d=9 row (G center)
        float wn[12];
        if constexpr (KQ == 0) {
            ldwin<true,true>(wn, Lb, 0, ch, wq);
            fmadd4<-4>(acc[0], eg, wn); fmadd4<0>(acc[1], eg, wn); fmadd4<4>(acc[2], eg, wn);
            ldwin<true,true>(wn, Lb, 1, ch, wq);
            fmadd4<-3>(acc[3], eg, wn); fmadd4<0>(acc[4], eg, wn); fmadd4<3>(acc[5], eg, wn);
            ldwin<true,true>(wn, Lb, 2, ch, wq);
            fmadd4<-2>(acc[6], eg, wn); fmadd4<0>(acc[7], eg, wn); fmadd4<2>(acc[8], eg, wn);
        } else if constexpr (KQ == 1) {
            ldwin<true,true>(wn, Lb, 3, ch, wq);
            fmadd4<-1>(acc[0], eg, wn); fmadd4<0>(acc[1], eg, wn); fmadd4<1>(acc[2], eg, wn);
            ldwin<true,false>(wn, Lb, 4, ch, wq);      // dy<0 only: t in [0,6]
            fmadd4<-1>(acc[3], eg, wn); fmadd4<-2>(acc[4], eg, wn);
            fmadd4<-3>(acc[5], eg, wn); fmadd4<-4>(acc[6], eg, wn);
        } else if constexpr (KQ == 2) {
            ldwin<false,true>(wn, Lb, 4, ch, wq);      // dy>=0 only: t in [4,11]
            fmadd4<0>(acc[0], eg, wn); fmadd4<1>(acc[1], eg, wn); fmadd4<2>(acc[2], eg, wn);
            fmadd4<3>(acc[3], eg, wn); fmadd4<4>(acc[4], eg, wn);
            ldwin<true,true>(wn, Lb, 5, ch, wq);
            fmadd4<-1>(acc[5], eg, wn); fmadd4<0>(acc[6], eg, wn); fmadd4<1>(acc[7], eg, wn);
        } else {
            ldwin<true,true>(wn, Lb, 6, ch, wq);
            fmadd4<-2>(acc[0], eg, wn); fmadd4<0>(acc[1], eg, wn); fmadd4<2>(acc[2], eg, wn);
            ldwin<true,true>(wn, Lb, 7, ch, wq);
            fmadd4<-3>(acc[3], eg, wn); fmadd4<0>(acc[4], eg, wn); fmadd4<3>(acc[5], eg, wn);
            ldwin<true,true>(wn, Lb, 8, ch, wq);
            fmadd4<-4>(acc[6], eg, wn); fmadd4<0>(acc[7], eg, wn); fmadd4<4>(acc[8], eg, wn);
        }
    }
}

__global__ __launch_bounds__(256, 2) void aff_part(
    const float* __restrict__ Ftg, const float* __restrict__ Gc,
    float* __restrict__ part)
{
    __shared__ float L[2][10 * 8 * 72];   // [d][ch][72]

    const int h = blockIdx.x, b = blockIdx.y, cseg = blockIdx.z;
    const int tid = threadIdx.x;
    const int wq = tid & 15, cg = (tid >> 4) & 3, kq = tid >> 6;  // kq wave-uniform
    const size_t plane = (size_t)b * 256 * 4096;
    const float* FtB = Ftg + plane;
    const float* GB  = Gc + plane;
    const int cbase = cseg * 64;

    int hr[10];
    #pragma unroll
    for (int d = 0; d < 10; ++d) hr[d] = (d < 9) ? iclamp(h + d - 4, 0, 63) : h;

    f4 vreg[5]; float sreg[3];

    auto load_rnd = [&](int rr) {
        const int c0 = cbase + rr * 8;
        #pragma unroll
        for (int i = 0; i < 5; ++i) {
            int f = i * 256 + tid, d = f >> 7, rem = f & 127, ch = rem >> 4, c4 = rem & 15;
            const float* src = (d < 9) ? FtB : GB;
            vreg[i] = *(const f4*)&src[(size_t)(c0 + ch) * 4096 + hr[d] * 64 + c4 * 4];
        }
        #pragma unroll
        for (int i = 0; i < 3; ++i) {
            int e = i * 256 + tid;
            if (e < 640) {
                int row = e >> 3, sc = e & 7, d = row >> 3, ch = row & 7;
                int wsrc = (sc < 4) ? 0 : 63;
                const float* src = (d < 9) ? FtB : GB;
                sreg[i] = src[(size_t)(c0 + ch) * 4096 + hr[d] * 64 + wsrc];
            }
        }
    };
    auto store_rnd = [&](int buf) {
        float* Lb = L[buf];
        #pragma unroll
        for (int i = 0; i < 5; ++i) {
            int f = i * 256 + tid, d = f >> 7, rem = f & 127, ch = rem >> 4, c4 = rem & 15;
            *(f4*)&Lb[(d * 8 + ch) * 72 + 4 + c4 * 4] = vreg[i];
        }
        #pragma unroll
        for (int i = 0; i < 3; ++i) {
            int e = i * 256 + tid;
            if (e < 640) {
                int row = e >> 3, sc = e & 7, d = row >> 3, ch = row & 7;
                int col = (sc < 4) ? sc : (64 + sc);
                Lb[(d * 8 + ch) * 72 + col] = sreg[i];
            }
        }
    };

    f4 acc[9] = {};

    load_rnd(0); store_rnd(0);
    for (int rr = 0; rr < 8; ++rr) {
        if (rr < 7) load_rnd(rr + 1);
        __syncthreads();
        const float* Lb = L[rr & 1];
        switch (kq) {                      // wave-uniform
            case 0: aff_compute<0>(Lb, wq, cg, acc); break;
            case 1: aff_compute<1>(Lb, wq, cg, acc); break;
            case 2: aff_compute<2>(Lb, wq, cg, acc); break;
            default: aff_compute<3>(Lb, wq, cg, acc); break;
        }
        if (rr < 7) store_rnd((rr + 1) & 1);
    }

    // butterfly-sum the 4 cg channel-pair partials (lane bits 4,5)
    #pragma unroll
    for (int j = 0; j < 9; ++j) {
        acc[j].x += __shfl_xor(acc[j].x, 16); acc[j].x += __shfl_xor(acc[j].x, 32);
        acc[j].y += __shfl_xor(acc[j].y, 16); acc[j].y += __shfl_xor(acc[j].y, 32);
        acc[j].z += __shfl_xor(acc[j].z, 16); acc[j].z += __shfl_xor(acc[j].z, 32);
        acc[j].w += __shfl_xor(acc[j].w, 16); acc[j].w += __shfl_xor(acc[j].w, 32);
    }

    if (cg == 0) {
        float* pB = part + (((size_t)cseg * 2 + b) * 33) * 4096 + h * 64 + wq * 4;
        #define STP(K, J) *(f4*)&pB[(size_t)(K) * 4096] = acc[J];
        switch (kq) {
            case 0: STP(25,0) STP(26,1) STP(27,2) STP(17,3) STP(18,4) STP(19,5) STP(9,6) STP(10,7) STP(11,8) break;
            case 1: STP(1,0) STP(2,1) STP(3,2) STP(4,3) STP(12,4) STP(20,5) STP(28,6) break;
            case 2: STP(0,0) STP(5,1) STP(13,2) STP(21,3) STP(29,4) STP(6,5) STP(7,6) STP(8,7) break;
            default: STP(14,0) STP(15,1) STP(16,2) STP(22,3) STP(23,4) STP(24,5) STP(30,6) STP(31,7) STP(32,8) break;
        }
        #undef STP
    }
}

// ---------------------------------------------------------------------------
// out (fused softmax): per thread, sum 4 cseg partials -> mask -> softmax
// (4-way redundant across cg waves; part L2-resident), then
// out[c][p] = sum_k wgt[k,p]*Ft[c,p+off_k].
// ---------------------------------------------------------------------------
__global__ __launch_bounds__(256, 2) void out_kernel(
    const float* __restrict__ part, const float* __restrict__ Ft,
    float* __restrict__ out)
{
    __shared__ float L[2][9 * 8 * 72];

    const int h = blockIdx.x, b = blockIdx.y, cseg = blockIdx.z;
    const int tid = threadIdx.x;
    const int w = tid & 63, cg = tid >> 6;    // cg wave-uniform
    const size_t plane = (size_t)b * 256 * 4096;
    const float* FtB = Ft + plane;
    float* outB = out + plane;
    const int cbase = cseg * 64;
    const int p = h * 64 + w;

    int hr[9];
    #pragma unroll
    for (int d = 0; d < 9; ++d) hr[d] = iclamp(h + d - 4, 0, 63);

    f4 vreg[5]; float sreg[3];

    auto load_rnd = [&](int rr) {
        const int c0 = cbase + rr * 8;
        #pragma unroll
        for (int i = 0; i < 5; ++i) {
            int f = i * 256 + tid;
            if (f < 1152) {
                int d = f >> 7, rem = f & 127, ch = rem >> 4, c4 = rem & 15;
                vreg[i] = *(const f4*)&FtB[(size_t)(c0 + ch) * 4096 + hr[d] * 64 + c4 * 4];
            }
        }
        #pragma unroll
        for (int i = 0; i < 3; ++i) {
            int e = i * 256 + tid;
            if (e < 576) {
                int row = e >> 3, sc = e & 7, d = row >> 3, ch = row & 7;
                int wsrc = (sc < 4) ? 0 : 63;
                sreg[i] = FtB[(size_t)(c0 + ch) * 4096 + hr[d] * 64 + wsrc];
            }
        }
    };
    auto store_rnd = [&](int buf) {
        float* Lb = L[buf];
        #pragma unroll
        for (int i = 0; i < 5; ++i) {
            int f = i * 256 + tid;
            if (f < 1152) {
                int d = f >> 7, rem = f & 127, ch = rem >> 4, c4 = rem & 15;
                *(f4*)&Lb[(d * 8 + ch) * 72 + 4 + c4 * 4] = vreg[i];
            }
        }
        #pragma unroll
        for (int i = 0; i < 3; ++i) {
            int e = i * 256 + tid;
            if (e < 576) {
                int row = e >> 3, sc = e & 7, d = row >> 3, ch = row & 7;
                int col = (sc < 4) ? sc : (64 + sc);
                Lb[(d * 8 + ch) * 72 + col] = sreg[i];
            }
        }
    };

    load_rnd(0);

    // ---- per-pixel softmax over k ----
    float wv[33];
    {
        constexpr size_t CS = (size_t)2 * 33 * 4096;   // cseg stride in part
        const float* pB = part + ((size_t)b * 33) * 4096 + p;
        float mx = -INFINITY;
        #pragma unroll
        for (int k = 0; k < 33; ++k) {
            size_t off = (size_t)k * 4096;
            float s = pB[off] + pB[CS + off] + pB[2 * CS + off] + pB[3 * CS + off];
            bool valid = ((unsigned)(h + DXC[k]) < 64u) && ((unsigned)(w + DYC[k]) < 64u);
            wv[k] = valid ? s : -INFINITY;
            mx = fmaxf(mx, wv[k]);
        }
        float ssum = 0.f;
        #pragma unroll
        for (int k = 0; k < 33; ++k) { float e = __expf(wv[k] - mx); wv[k] = e; ssum += e; }
        float inv = 1.0f / ssum;
        #pragma unroll
        for (int k = 0; k < 33; ++k) wv[k] *= inv;
    }

    store_rnd(0);
    for (int rr = 0; rr < 8; ++rr) {
        if (rr < 7) load_rnd(rr + 1);
        __syncthreads();
        const float* base = &L[rr & 1][4 + w];
        #pragma unroll
        for (int u = 0; u < 2; ++u) {
            const float* b2 = base + (cg * 2 + u) * 72;
            float o = 0.f;
            #pragma unroll
            for (int k = 0; k < 33; ++k)
                o += wv[k] * b2[(DXC[k] + 4) * 576 + DYC[k]];
            int c = cbase + rr * 8 + cg * 2 + u;
            outB[(size_t)c * 4096 + p] = o;
        }
        if (rr < 7) store_rnd((rr + 1) & 1);
    }
}

// ---------------------------------------------------------------------------
extern "C" void kernel_launch(void* const* d_in, const int* in_sizes, int n_in,
                              void* d_out, int out_size, void* d_ws, size_t ws_size,
                              hipStream_t stream) {
    const float* Ft  = (const float*)d_in[0];
    const float* FtE = (const float*)d_in[1];
    const float* Wf  = (const float*)d_in[2];
    const float* bf  = (const float*)d_in[3];
    const float* Wg  = (const float*)d_in[4];
    const float* bg  = (const float*)d_in[5];
    float* out = (float*)d_out;
    (void)bf;   // bf contributes only a k-constant -> cancelled by softmax

    // ws: G 8.4MB | part 4.3MB | Mt 256KB | r 1KB
    float* G    = (float*)d_ws;
    float* part = G + (size_t)2 * 256 * 4096;        // [4 cseg][2 b][33][4096]
    float* Mt   = part + (size_t)4 * 2 * 33 * 4096;  // [256 k][256 m] (transposed)
    float* rw   = Mt + 256 * 256;                    // [256]

    hipLaunchKernelGGL(mat_M,      dim3(8, 8),     dim3(256), 0, stream, Wf, Wg, bg, Mt, rw);
    hipLaunchKernelGGL(gemm_G,     dim3(512),      dim3(256), 0, stream, Mt, rw, FtE, G);
    hipLaunchKernelGGL(aff_part,   dim3(64, 2, 4), dim3(256), 0, stream, Ft, G, part);
    hipLaunchKernelGGL(out_kernel, dim3(64, 2, 4), dim3(256), 0, stream, part, Ft, out);
}

// Round 6
// 144.488 us; speedup vs baseline: 1.1172x; 1.1172x over previous
//
#include <hip/hip_runtime.h>
#include <math.h>

// B=2, C=O=256, H=W=64, K=33 offsets (D=4 rings).
//
// Algebra: aff[k,p] = Eg(p)·Ef(p_k) = G(p)·Ft(p_k) + const(p), with
// G = (Wf^T Wg)·Ftε + Wf^T bg; const(p) cancels in softmax.
// Pipeline: mat_M (64 blk, emits Mt[k][m]) -> gemm_G (512 blk, Mt in LDS,
// X streamed w/ 8-deep reg pipeline) -> aff_part (windowed b128)
// -> out_kernel (fused softmax).
typedef __attribute__((ext_vector_type(4))) float f4;

__device__ __forceinline__ int iclamp(int x, int lo, int hi) { return min(max(x, lo), hi); }

// k=0:(0,0); rings s=1..4: (-s,-s),(-s,0),(-s,s),(0,-s),(0,s),(s,-s),(s,0),(s,s)
__device__ constexpr int DXC[33] = {0, -1,-1,-1,0,0,1,1,1, -2,-2,-2,0,0,2,2,2, -3,-3,-3,0,0,3,3,3, -4,-4,-4,0,0,4,4,4};
__device__ constexpr int DYC[33] = {0, -1,0,1,-1,1,-1,0,1, -2,0,2,-2,2,-2,0,2, -3,0,3,-3,3,-3,0,3, -4,0,4,-4,4,-4,0,4};

// ---------------------------------------------------------------------------
// mat_M: Mt[c2][c1] = sum_o Wf[o,c1]*Wg[o,c2]  (transposed for gemm_G)
//        r[c1]     = sum_o Wf[o,c1]*bg[o]
// grid (8,8) = 64 blocks (32x32 tiles, 2x2 acc).
// ---------------------------------------------------------------------------
__global__ __launch_bounds__(256) void mat_M(
    const float* __restrict__ Wf, const float* __restrict__ Wg,
    const float* __restrict__ bg, float* __restrict__ Mt, float* __restrict__ r)
{
    __shared__ float Sf[32][33], Sg[32][33];
    __shared__ float Rs[32][9];
    const int c1b = blockIdx.x * 32, c2b = blockIdx.y * 32;
    const int tid = threadIdx.x;
    const int tx = tid & 15, ty = tid >> 4;
    float acc[2][2] = {};
    for (int ko = 0; ko < 256; ko += 32) {
        #pragma unroll
        for (int i = 0; i < 4; ++i) {
            int f = i * 256 + tid, o = f >> 5, c = f & 31;
            Sf[o][c] = Wf[(ko + o) * 256 + c1b + c];
            Sg[o][c] = Wg[(ko + o) * 256 + c2b + c];
        }
        __syncthreads();
        #pragma unroll
        for (int o = 0; o < 32; ++o) {
            float f0 = Sf[o][ty * 2], f1 = Sf[o][ty * 2 + 1];
            float g0 = Sg[o][tx * 2], g1 = Sg[o][tx * 2 + 1];
            acc[0][0] += f0 * g0; acc[0][1] += f0 * g1;
            acc[1][0] += f1 * g0; acc[1][1] += f1 * g1;
        }
        __syncthreads();
    }
    #pragma unroll
    for (int i = 0; i < 2; ++i)
        #pragma unroll
        for (int j = 0; j < 2; ++j)
            Mt[(size_t)(c2b + tx * 2 + j) * 256 + c1b + ty * 2 + i] = acc[i][j];

    if (blockIdx.y == 0) {   // block-uniform
        const int c1l = tid & 31, og = tid >> 5;
        float s = 0.f;
        #pragma unroll 8
        for (int o = og * 32; o < og * 32 + 32; ++o)
            s += Wf[o * 256 + c1b + c1l] * bg[o];
        Rs[c1l][og] = s;
        __syncthreads();
        if (tid < 32) {
            float t = 0.f;
            #pragma unroll
            for (int j = 0; j < 8; ++j) t += Rs[tid][j];
            r[c1b + tid] = t;
        }
    }
}

// ---------------------------------------------------------------------------
// gemm_G v4: G[b][m][p] = sum_k Mt[k][m]*Ftε[b][k][p] + r[m].
// Grid 512 (bn 0..63, bm 0..3, b 0..1): 64x64 tile, 4m x 4n acc/thread.
// Whole Mt m-slice (256k x 64m = 64 KB) staged in LDS ONCE (one barrier,
// none in k-loop). X streamed from L2 with explicit 8-deep named-register
// pipeline (keeps ~8 VMEM in flight; R5's unroll-pragma version register-
// starved to VGPR=36 and serialized at ~220 cyc/load -> 47 µs).
// ---------------------------------------------------------------------------
__global__ __launch_bounds__(256, 2) void gemm_G(
    const float* __restrict__ Mt, const float* __restrict__ r,
    const float* __restrict__ FtE, float* __restrict__ G)
{
    __shared__ float Ms[256][64];   // [k][m-slice] = 64 KB
    const int bid = blockIdx.x;
    const int bn = bid & 63, bm = (bid >> 6) & 3, b = bid >> 8;
    const int tid = threadIdx.x;
    const int tn = tid & 15, tm = tid >> 4;
    const int m0 = bm * 64;
    const int m0g = m0 + tm * 4;
    const int n0g = bn * 64 + tn * 4;
    const float* X = FtE + (size_t)b * 1048576 + n0g;    // + k*4096

    // stage Mt slice (coalesced; L2-resident 256 KB operand)
    #pragma unroll
    for (int i = 0; i < 16; ++i) {
        int f = i * 256 + tid;
        int k = f >> 4, mi = f & 15;
        *(f4*)&Ms[k][mi * 4] = *(const f4*)&Mt[(size_t)k * 256 + m0 + mi * 4];
    }
    __syncthreads();

    f4 acc0 = {0.f,0.f,0.f,0.f}, acc1 = acc0, acc2 = acc0, acc3 = acc0;

    for (int kc = 0; kc < 256; kc += 8) {
        // 8 independent VMEM loads (named regs -> all in flight)
        f4 x0 = *(const f4*)(X + (size_t)(kc + 0) * 4096);
        f4 x1 = *(const f4*)(X + (size_t)(kc + 1) * 4096);
        f4 x2 = *(const f4*)(X + (size_t)(kc + 2) * 4096);
        f4 x3 = *(const f4*)(X + (size_t)(kc + 3) * 4096);
        f4 x4 = *(const f4*)(X + (size_t)(kc + 4) * 4096);
        f4 x5 = *(const f4*)(X + (size_t)(kc + 5) * 4096);
        f4 x6 = *(const f4*)(X + (size_t)(kc + 6) * 4096);
        f4 x7 = *(const f4*)(X + (size_t)(kc + 7) * 4096);
        // 8 LDS reads (4 distinct addr/wave, broadcast; 2-way alias = free)
        f4 a0 = *(const f4*)&Ms[kc + 0][tm * 4];
        f4 a1 = *(const f4*)&Ms[kc + 1][tm * 4];
        f4 a2 = *(const f4*)&Ms[kc + 2][tm * 4];
        f4 a3 = *(const f4*)&Ms[kc + 3][tm * 4];
        f4 a4 = *(const f4*)&Ms[kc + 4][tm * 4];
        f4 a5 = *(const f4*)&Ms[kc + 5][tm * 4];
        f4 a6 = *(const f4*)&Ms[kc + 6][tm * 4];
        f4 a7 = *(const f4*)&Ms[kc + 7][tm * 4];
        acc0 += x0 * a0.x; acc1 += x0 * a0.y; acc2 += x0 * a0.z; acc3 += x0 * a0.w;
        acc0 += x1 * a1.x; acc1 += x1 * a1.y; acc2 += x1 * a1.z; acc3 += x1 * a1.w;
        acc0 += x2 * a2.x; acc1 += x2 * a2.y; acc2 += x2 * a2.z; acc3 += x2 * a2.w;
        acc0 += x3 * a3.x; acc1 += x3 * a3.y; acc2 += x3 * a3.z; acc3 += x3 * a3.w;
        acc0 += x4 * a4.x; acc1 += x4 * a4.y; acc2 += x4 * a4.z; acc3 += x4 * a4.w;
        acc0 += x5 * a5.x; acc1 += x5 * a5.y; acc2 += x5 * a5.z; acc3 += x5 * a5.w;
        acc0 += x6 * a6.x; acc1 += x6 * a6.y; acc2 += x6 * a6.z; acc3 += x6 * a6.w;
        acc0 += x7 * a7.x; acc1 += x7 * a7.y; acc2 += x7 * a7.z; acc3 += x7 * a7.w;
    }

    float* Gp = G + (size_t)b * 1048576;
    {
        f4 v;
        v = acc0 + r[m0g + 0]; *(f4*)&Gp[(size_t)(m0g + 0) * 4096 + n0g] = v;
        v = acc1 + r[m0g + 1]; *(f4*)&Gp[(size_t)(m0g + 1) * 4096 + n0g] = v;
        v = acc2 + r[m0g + 2]; *(f4*)&Gp[(size_t)(m0g + 2) * 4096 + n0g] = v;
        v = acc3 + r[m0g + 3]; *(f4*)&Gp[(size_t)(m0g + 3) * 4096 + n0g] = v;
    }
}

// ---------------------------------------------------------------------------
// Windowed-register helpers: a 12-wide row window (3 aligned b128 from LDS)
// serves all dy in [-4,4] for 4 consecutive pixels via compile-time indices.
// ---------------------------------------------------------------------------
template<bool LO, bool HI>
__device__ __forceinline__ void ldwin(float* wn, const float* Lb, int rd, int ch, int wq) {
    const float* p = &Lb[(rd * 8 + ch) * 72 + wq * 4];   // aligned: 72%4==0, wq*4
    if constexpr (LO) { f4 v = *(const f4*)p;       wn[0]=v.x; wn[1]=v.y; wn[2]=v.z;  wn[3]=v.w; }
    {                   f4 v = *(const f4*)(p + 4); wn[4]=v.x; wn[5]=v.y; wn[6]=v.z;  wn[7]=v.w; }
    if constexpr (HI) { f4 v = *(const f4*)(p + 8); wn[8]=v.x; wn[9]=v.y; wn[10]=v.z; wn[11]=v.w; }
}

// acc[px] += eg[px] * window[4 + px + DY]   (px = 0..3, all compile-time)
template<int DY>
__device__ __forceinline__ void fmadd4(f4& a, const f4& eg, const float* wn) {
    a.x += eg.x * wn[4 + DY];
    a.y += eg.y * wn[5 + DY];
    a.z += eg.z * wn[6 + DY];
    a.w += eg.w * wn[7 + DY];
}

// ---------------------------------------------------------------------------
// aff_part v3: part[cseg][b][k][p] = sum_{c in cseg's 64} G[c,p]*Ft[c,p+off_k]
// grid (64 h, 2 b, 4 cseg). Threads: wq=tid&15 (4 px), cg=(tid>>4)&3 (ch-pair),
// kq=tid>>6 (wave-uniform k-row split). Staging pre-clamped halos.
// Rows (rd = dx+4): rd4 = center (9 k), others 3 k each.
//   kq0: rd 0,1,2   kq1: rd3 + rd4(dy<0)   kq2: rd4(dy>=0) + rd5   kq3: rd 6,7,8
// Partials accumulate over rounds; one final shfl_xor butterfly over cg.
// ---------------------------------------------------------------------------
template<int KQ>
__device__ __forceinline__ void aff_compute(const float* Lb, int wq, int cg, f4* acc)
{
    #pragma unroll
    for (int chi = 0; chi < 2; ++chi) {
        const int ch = cg * 2 + chi;
        f4 eg = *(const f4*)&Lb[(72 + ch) * 72 + 4 + wq * 4];   // d=9 row (G center)
        float wn[12];
        if constexpr (KQ == 0) {
            ldwin<true,true>(wn, Lb, 0, ch, wq);
            fmadd4<-4>(acc[0], eg, wn); fmadd4<0>(acc[1], eg, wn); fmadd4<4>(acc[2], eg, wn);
            ldwin<true,true>(wn, Lb, 1, ch, wq);
            fmadd4<-3>(acc[3], eg, wn); fmadd4<0>(acc[4], eg, wn); fmadd4<3>(acc[5], eg, wn);
            ldwin<true,true>(wn, Lb, 2, ch, wq);
            fmadd4<-2>(acc[6], eg, wn); fmadd4<0>(acc[7], eg, wn); fmadd4<2>(acc[8], eg, wn);
        } else if constexpr (KQ == 1) {
            ldwin<true,true>(wn, Lb, 3, ch, wq);
            fmadd4<-1>(acc[0], eg, wn); fmadd4<0>(acc[1], eg, wn); fmadd4<1>(acc[2], eg, wn);
            ldwin<true,false>(wn, Lb, 4, ch, wq);      // dy<0 only: t in [0,6]
            fmadd4<-1>(acc[3], eg, wn); fmadd4<-2>(acc[4], eg, wn);
            fmadd4<-3>(acc[5], eg, wn); fmadd4<-4>(acc[6], eg, wn);
        } else if constexpr (KQ == 2) {
            ldwin<false,true>(wn, Lb, 4, ch, wq);      // dy>=0 only: t in [4,11]
            fmadd4<0>(acc[0], eg, wn); fmadd4<1>(acc[1], eg, wn); fmadd4<2>(acc[2], eg, wn);
            fmadd4<3>(acc[3], eg, wn); fmadd4<4>(acc[4], eg, wn);
            ldwin<true,true>(wn, Lb, 5, ch, wq);
            fmadd4<-1>(acc[5], eg, wn); fmadd4<0>(acc[6], eg, wn); fmadd4<1>(acc[7], eg, wn);
        } else {
            ldwin<true,true>(wn, Lb, 6, ch, wq);
            fmadd4<-2>(acc[0], eg, wn); fmadd4<0>(acc[1], eg, wn); fmadd4<2>(acc[2], eg, wn);
            ldwin<true,true>(wn, Lb, 7, ch, wq);
            fmadd4<-3>(acc[3], eg, wn); fmadd4<0>(acc[4], eg, wn); fmadd4<3>(acc[5], eg, wn);
            ldwin<true,true>(wn, Lb, 8, ch, wq);
            fmadd4<-4>(acc[6], eg, wn); fmadd4<0>(acc[7], eg, wn); fmadd4<4>(acc[8], eg, wn);
        }
    }
}

__global__ __launch_bounds__(256, 2) void aff_part(
    const float* __restrict__ Ftg, const float* __restrict__ Gc,
    float* __restrict__ part)
{
    __shared__ float L[2][10 * 8 * 72];   // [d][ch][72]

    const int h = blockIdx.x, b = blockIdx.y, cseg = blockIdx.z;
    const int tid = threadIdx.x;
    const int wq = tid & 15, cg = (tid >> 4) & 3, kq = tid >> 6;  // kq wave-uniform
    const size_t plane = (size_t)b * 256 * 4096;
    const float* FtB = Ftg + plane;
    const float* GB  = Gc + plane;
    const int cbase = cseg * 64;

    int hr[10];
    #pragma unroll
    for (int d = 0; d < 10; ++d) hr[d] = (d < 9) ? iclamp(h + d - 4, 0, 63) : h;

    f4 vreg[5]; float sreg[3];

    auto load_rnd = [&](int rr) {
        const int c0 = cbase + rr * 8;
        #pragma unroll
        for (int i = 0; i < 5; ++i) {
            int f = i * 256 + tid, d = f >> 7, rem = f & 127, ch = rem >> 4, c4 = rem & 15;
            const float* src = (d < 9) ? FtB : GB;
            vreg[i] = *(const f4*)&src[(size_t)(c0 + ch) * 4096 + hr[d] * 64 + c4 * 4];
        }
        #pragma unroll
        for (int i = 0; i < 3; ++i) {
            int e = i * 256 + tid;
            if (e < 640) {
                int row = e >> 3, sc = e & 7, d = row >> 3, ch = row & 7;
                int wsrc = (sc < 4) ? 0 : 63;
                const float* src = (d < 9) ? FtB : GB;
                sreg[i] = src[(size_t)(c0 + ch) * 4096 + hr[d] * 64 + wsrc];
            }
        }
    };
    auto store_rnd = [&](int buf) {
        float* Lb = L[buf];
        #pragma unroll
        for (int i = 0; i < 5; ++i) {
            int f = i * 256 + tid, d = f >> 7, rem = f & 127, ch = rem >> 4, c4 = rem & 15;
            *(f4*)&Lb[(d * 8 + ch) * 72 + 4 + c4 * 4] = vreg[i];
        }
        #pragma unroll
        for (int i = 0; i < 3; ++i) {
            int e = i * 256 + tid;
            if (e < 640) {
                int row = e >> 3, sc = e & 7, d = row >> 3, ch = row & 7;
                int col = (sc < 4) ? sc : (64 + sc);
                Lb[(d * 8 + ch) * 72 + col] = sreg[i];
            }
        }
    };

    f4 acc[9] = {};

    load_rnd(0); store_rnd(0);
    for (int rr = 0; rr < 8; ++rr) {
        if (rr < 7) load_rnd(rr + 1);
        __syncthreads();
        const float* Lb = L[rr & 1];
        switch (kq) {                      // wave-uniform
            case 0: aff_compute<0>(Lb, wq, cg, acc); break;
            case 1: aff_compute<1>(Lb, wq, cg, acc); break;
            case 2: aff_compute<2>(Lb, wq, cg, acc); break;
            default: aff_compute<3>(Lb, wq, cg, acc); break;
        }
        if (rr < 7) store_rnd((rr + 1) & 1);
    }

    // butterfly-sum the 4 cg channel-pair partials (lane bits 4,5)
    #pragma unroll
    for (int j = 0; j < 9; ++j) {
        acc[j].x += __shfl_xor(acc[j].x, 16); acc[j].x += __shfl_xor(acc[j].x, 32);
        acc[j].y += __shfl_xor(acc[j].y, 16); acc[j].y += __shfl_xor(acc[j].y, 32);
        acc[j].z += __shfl_xor(acc[j].z, 16); acc[j].z += __shfl_xor(acc[j].z, 32);
        acc[j].w += __shfl_xor(acc[j].w, 16); acc[j].w += __shfl_xor(acc[j].w, 32);
    }

    if (cg == 0) {
        float* pB = part + (((size_t)cseg * 2 + b) * 33) * 4096 + h * 64 + wq * 4;
        #define STP(K, J) *(f4*)&pB[(size_t)(K) * 4096] = acc[J];
        switch (kq) {
            case 0: STP(25,0) STP(26,1) STP(27,2) STP(17,3) STP(18,4) STP(19,5) STP(9,6) STP(10,7) STP(11,8) break;
            case 1: STP(1,0) STP(2,1) STP(3,2) STP(4,3) STP(12,4) STP(20,5) STP(28,6) break;
            case 2: STP(0,0) STP(5,1) STP(13,2) STP(21,3) STP(29,4) STP(6,5) STP(7,6) STP(8,7) break;
            default: STP(14,0) STP(15,1) STP(16,2) STP(22,3) STP(23,4) STP(24,5) STP(30,6) STP(31,7) STP(32,8) break;
        }
        #undef STP
    }
}

// ---------------------------------------------------------------------------
// out (fused softmax): per thread, sum 4 cseg partials -> mask -> softmax
// (4-way redundant across cg waves; part L2-resident), then
// out[c][p] = sum_k wgt[k,p]*Ft[c,p+off_k].
// ---------------------------------------------------------------------------
__global__ __launch_bounds__(256, 2) void out_kernel(
    const float* __restrict__ part, const float* __restrict__ Ft,
    float* __restrict__ out)
{
    __shared__ float L[2][9 * 8 * 72];

    const int h = blockIdx.x, b = blockIdx.y, cseg = blockIdx.z;
    const int tid = threadIdx.x;
    const int w = tid & 63, cg = tid >> 6;    // cg wave-uniform
    const size_t plane = (size_t)b * 256 * 4096;
    const float* FtB = Ft + plane;
    float* outB = out + plane;
    const int cbase = cseg * 64;
    const int p = h * 64 + w;

    int hr[9];
    #pragma unroll
    for (int d = 0; d < 9; ++d) hr[d] = iclamp(h + d - 4, 0, 63);

    f4 vreg[5]; float sreg[3];

    auto load_rnd = [&](int rr) {
        const int c0 = cbase + rr * 8;
        #pragma unroll
        for (int i = 0; i < 5; ++i) {
            int f = i * 256 + tid;
            if (f < 1152) {
                int d = f >> 7, rem = f & 127, ch = rem >> 4, c4 = rem & 15;
                vreg[i] = *(const f4*)&FtB[(size_t)(c0 + ch) * 4096 + hr[d] * 64 + c4 * 4];
            }
        }
        #pragma unroll
        for (int i = 0; i < 3; ++i) {
            int e = i * 256 + tid;
            if (e < 576) {
                int row = e >> 3, sc = e & 7, d = row >> 3, ch = row & 7;
                int wsrc = (sc < 4) ? 0 : 63;
                sreg[i] = FtB[(size_t)(c0 + ch) * 4096 + hr[d] * 64 + wsrc];
            }
        }
    };
    auto store_rnd = [&](int buf) {
        float* Lb = L[buf];
        #pragma unroll
        for (int i = 0; i < 5; ++i) {
            int f = i * 256 + tid;
            if (f < 1152) {
                int d = f >> 7, rem = f & 127, ch = rem >> 4, c4 = rem & 15;
                *(f4*)&Lb[(d * 8 + ch) * 72 + 4 + c4 * 4] = vreg[i];
            }
        }
        #pragma unroll
        for (int i = 0; i < 3; ++i) {
            int e = i * 256 + tid;
            if (e < 576) {
                int row = e >> 3, sc = e & 7, d = row >> 3, ch = row & 7;
                int col = (sc < 4) ? sc : (64 + sc);
                Lb[(d * 8 + ch) * 72 + col] = sreg[i];
            }
        }
    };

    load_rnd(0);

    // ---- per-pixel softmax over k ----
    float wv[33];
    {
        constexpr size_t CS = (size_t)2 * 33 * 4096;   // cseg stride in part
        const float* pB = part + ((size_t)b * 33) * 4096 + p;
        float mx = -INFINITY;
        #pragma unroll
        for (int k = 0; k < 33; ++k) {
            size_t off = (size_t)k * 4096;
            float s = pB[off] + pB[CS + off] + pB[2 * CS + off] + pB[3 * CS + off];
            bool valid = ((unsigned)(h + DXC[k]) < 64u) && ((unsigned)(w + DYC[k]) < 64u);
            wv[k] = valid ? s : -INFINITY;
            mx = fmaxf(mx, wv[k]);
        }
        float ssum = 0.f;
        #pragma unroll
        for (int k = 0; k < 33; ++k) { float e = __expf(wv[k] - mx); wv[k] = e; ssum += e; }
        float inv = 1.0f / ssum;
        #pragma unroll
        for (int k = 0; k < 33; ++k) wv[k] *= inv;
    }

    store_rnd(0);
    for (int rr = 0; rr < 8; ++rr) {
        if (rr < 7) load_rnd(rr + 1);
        __syncthreads();
        const float* base = &L[rr & 1][4 + w];
        #pragma unroll
        for (int u = 0; u < 2; ++u) {
            const float* b2 = base + (cg * 2 + u) * 72;
            float o = 0.f;
            #pragma unroll
            for (int k = 0; k < 33; ++k)
                o += wv[k] * b2[(DXC[k] + 4) * 576 + DYC[k]];
            int c = cbase + rr * 8 + cg * 2 + u;
            outB[(size_t)c * 4096 + p] = o;
        }
        if (rr < 7) store_rnd((rr + 1) & 1);
    }
}

// ---------------------------------------------------------------------------
extern "C" void kernel_launch(void* const* d_in, const int* in_sizes, int n_in,
                              void* d_out, int out_size, void* d_ws, size_t ws_size,
                              hipStream_t stream) {
    const float* Ft  = (const float*)d_in[0];
    const float* FtE = (const float*)d_in[1];
    const float* Wf  = (const float*)d_in[2];
    const float* bf  = (const float*)d_in[3];
    const float* Wg  = (const float*)d_in[4];
    const float* bg  = (const float*)d_in[5];
    float* out = (float*)d_out;
    (void)bf;   // bf contributes only a k-constant -> cancelled by softmax

    // ws: G 8.4MB | part 4.3MB | Mt 256KB | r 1KB
    float* G    = (float*)d_ws;
    float* part = G + (size_t)2 * 256 * 4096;        // [4 cseg][2 b][33][4096]
    float* Mt   = part + (size_t)4 * 2 * 33 * 4096;  // [256 k][256 m] (transposed)
    float* rw   = Mt + 256 * 256;                    // [256]

    hipLaunchKernelGGL(mat_M,      dim3(8, 8),     dim3(256), 0, stream, Wf, Wg, bg, Mt, rw);
    hipLaunchKernelGGL(gemm_G,     dim3(512),      dim3(256), 0, stream, Mt, rw, FtE, G);
    hipLaunchKernelGGL(aff_part,   dim3(64, 2, 4), dim3(256), 0, stream, Ft, G, part);
    hipLaunchKernelGGL(out_kernel, dim3(64, 2, 4), dim3(256), 0, stream, part, Ft, out);
}

// Round 7
// 140.532 us; speedup vs baseline: 1.1486x; 1.0282x over previous
//
#include <hip/hip_runtime.h>
#include <math.h>

// B=2, C=O=256, H=W=64, K=33 offsets (D=4 rings).
//
// Algebra: aff[k,p] = Eg(p)·Ef(p_k) = G(p)·Ft(p_k) + const(p), with
// G = (Wf^T Wg)·Ftε + Wf^T bg; const(p) cancels in softmax.
// Fusion: gemm_G's (bn,bm,b) tile == aff_part's (h,cseg,b) center operand,
// 1:1 -> compute G-tile in-block (phase A) and consume from LDS (phase B).
// Pipeline: mat_M (64 blk) -> gemm_aff (512 blk) -> out_kernel (512 blk).
typedef __attribute__((ext_vector_type(4))) float f4;

__device__ __forceinline__ int iclamp(int x, int lo, int hi) { return min(max(x, lo), hi); }

// k=0:(0,0); rings s=1..4: (-s,-s),(-s,0),(-s,s),(0,-s),(0,s),(s,-s),(s,0),(s,s)
__device__ constexpr int DXC[33] = {0, -1,-1,-1,0,0,1,1,1, -2,-2,-2,0,0,2,2,2, -3,-3,-3,0,0,3,3,3, -4,-4,-4,0,0,4,4,4};
__device__ constexpr int DYC[33] = {0, -1,0,1,-1,1,-1,0,1, -2,0,2,-2,2,-2,0,2, -3,0,3,-3,3,-3,0,3, -4,0,4,-4,4,-4,0,4};

// ---------------------------------------------------------------------------
// mat_M: Mt[c2][c1] = sum_o Wf[o,c1]*Wg[o,c2]  (transposed for gemm phase)
//        r[c1]     = sum_o Wf[o,c1]*bg[o]
// grid (8,8) = 64 blocks (32x32 tiles, 2x2 acc).
// ---------------------------------------------------------------------------
__global__ __launch_bounds__(256) void mat_M(
    const float* __restrict__ Wf, const float* __restrict__ Wg,
    const float* __restrict__ bg, float* __restrict__ Mt, float* __restrict__ r)
{
    __shared__ float Sf[32][33], Sg[32][33];
    __shared__ float Rs[32][9];
    const int c1b = blockIdx.x * 32, c2b = blockIdx.y * 32;
    const int tid = threadIdx.x;
    const int tx = tid & 15, ty = tid >> 4;
    float acc[2][2] = {};
    for (int ko = 0; ko < 256; ko += 32) {
        #pragma unroll
        for (int i = 0; i < 4; ++i) {
            int f = i * 256 + tid, o = f >> 5, c = f & 31;
            Sf[o][c] = Wf[(ko + o) * 256 + c1b + c];
            Sg[o][c] = Wg[(ko + o) * 256 + c2b + c];
        }
        __syncthreads();
        #pragma unroll
        for (int o = 0; o < 32; ++o) {
            float f0 = Sf[o][ty * 2], f1 = Sf[o][ty * 2 + 1];
            float g0 = Sg[o][tx * 2], g1 = Sg[o][tx * 2 + 1];
            acc[0][0] += f0 * g0; acc[0][1] += f0 * g1;
            acc[1][0] += f1 * g0; acc[1][1] += f1 * g1;
        }
        __syncthreads();
    }
    #pragma unroll
    for (int i = 0; i < 2; ++i)
        #pragma unroll
        for (int j = 0; j < 2; ++j)
            Mt[(size_t)(c2b + tx * 2 + j) * 256 + c1b + ty * 2 + i] = acc[i][j];

    if (blockIdx.y == 0) {   // block-uniform
        const int c1l = tid & 31, og = tid >> 5;
        float s = 0.f;
        #pragma unroll 8
        for (int o = og * 32; o < og * 32 + 32; ++o)
            s += Wf[o * 256 + c1b + c1l] * bg[o];
        Rs[c1l][og] = s;
        __syncthreads();
        if (tid < 32) {
            float t = 0.f;
            #pragma unroll
            for (int j = 0; j < 8; ++j) t += Rs[tid][j];
            r[c1b + tid] = t;
        }
    }
}

// ---------------------------------------------------------------------------
// Windowed-register helpers: a 12-wide row window (3 aligned b128 from LDS)
// serves all dy in [-4,4] for 4 consecutive pixels via compile-time indices.
// ---------------------------------------------------------------------------
template<bool LO, bool HI>
__device__ __forceinline__ void ldwin(float* wn, const float* Lb, int rd, int ch, int wq) {
    const float* p = &Lb[(rd * 8 + ch) * 72 + wq * 4];   // aligned: 72%4==0, wq*4
    if constexpr (LO) { f4 v = *(const f4*)p;       wn[0]=v.x; wn[1]=v.y; wn[2]=v.z;  wn[3]=v.w; }
    {                   f4 v = *(const f4*)(p + 4); wn[4]=v.x; wn[5]=v.y; wn[6]=v.z;  wn[7]=v.w; }
    if constexpr (HI) { f4 v = *(const f4*)(p + 8); wn[8]=v.x; wn[9]=v.y; wn[10]=v.z; wn[11]=v.w; }
}

// acc[px] += eg[px] * window[4 + px + DY]   (px = 0..3, all compile-time)
template<int DY>
__device__ __forceinline__ void fmadd4(f4& a, const f4& eg, const float* wn) {
    a.x += eg.x * wn[4 + DY];
    a.y += eg.y * wn[5 + DY];
    a.z += eg.z * wn[6 + DY];
    a.w += eg.w * wn[7 + DY];
}

// ---------------------------------------------------------------------------
// aff compute: eg (G center) from Gs[64][68] in LDS; Ft windows from L rows.
// Rows (rd = dx+4): rd4 = center (9 k), others 3 k each.
//   kq0: rd 0,1,2   kq1: rd3 + rd4(dy<0)   kq2: rd4(dy>=0) + rd5   kq3: rd 6,7,8
// ---------------------------------------------------------------------------
template<int KQ>
__device__ __forceinline__ void aff_compute(const float* Lb, const float* egb,
                                            int wq, int cg, f4* acc)
{
    #pragma unroll
    for (int chi = 0; chi < 2; ++chi) {
        const int ch = cg * 2 + chi;
        f4 eg = *(const f4*)&egb[ch * 68 + wq * 4];   // G-tile row (68-pad: bank spread)
        float wn[12];
        if constexpr (KQ == 0) {
            ldwin<true,true>(wn, Lb, 0, ch, wq);
            fmadd4<-4>(acc[0], eg, wn); fmadd4<0>(acc[1], eg, wn); fmadd4<4>(acc[2], eg, wn);
            ldwin<true,true>(wn, Lb, 1, ch, wq);
            fmadd4<-3>(acc[3], eg, wn); fmadd4<0>(acc[4], eg, wn); fmadd4<3>(acc[5], eg, wn);
            ldwin<true,true>(wn, Lb, 2, ch, wq);
            fmadd4<-2>(acc[6], eg, wn); fmadd4<0>(acc[7], eg, wn); fmadd4<2>(acc[8], eg, wn);
        } else if constexpr (KQ == 1) {
            ldwin<true,true>(wn, Lb, 3, ch, wq);
            fmadd4<-1>(acc[0], eg, wn); fmadd4<0>(acc[1], eg, wn); fmadd4<1>(acc[2], eg, wn);
            ldwin<true,false>(wn, Lb, 4, ch, wq);      // dy<0 only: t in [0,6]
            fmadd4<-1>(acc[3], eg, wn); fmadd4<-2>(acc[4], eg, wn);
            fmadd4<-3>(acc[5], eg, wn); fmadd4<-4>(acc[6], eg, wn);
        } else if constexpr (KQ == 2) {
            ldwin<false,true>(wn, Lb, 4, ch, wq);      // dy>=0 only: t in [4,11]
            fmadd4<0>(acc[0], eg, wn); fmadd4<1>(acc[1], eg, wn); fmadd4<2>(acc[2], eg, wn);
            fmadd4<3>(acc[3], eg, wn); fmadd4<4>(acc[4], eg, wn);
            ldwin<true,true>(wn, Lb, 5, ch, wq);
            fmadd4<-1>(acc[5], eg, wn); fmadd4<0>(acc[6], eg, wn); fmadd4<1>(acc[7], eg, wn);
        } else {
            ldwin<true,true>(wn, Lb, 6, ch, wq);
            fmadd4<-2>(acc[0], eg, wn); fmadd4<0>(acc[1], eg, wn); fmadd4<2>(acc[2], eg, wn);
            ldwin<true,true>(wn, Lb, 7, ch, wq);
            fmadd4<-3>(acc[3], eg, wn); fmadd4<0>(acc[4], eg, wn); fmadd4<3>(acc[5], eg, wn);
            ldwin<true,true>(wn, Lb, 8, ch, wq);
            fmadd4<-4>(acc[6], eg, wn); fmadd4<0>(acc[7], eg, wn); fmadd4<4>(acc[8], eg, wn);
        }
    }
}

// ---------------------------------------------------------------------------
// gemm_aff: block (h, b, cseg).
// Phase A: Gtile[ch][w] = sum_k Mt[k][cseg*64+ch]*Ftε[b][k][h*64+w] + r[..]
//   Ms[256][64] (64 KB) staged once; X streamed with 8-deep named-reg pipe.
// Phase B: part[cseg][b][k][p] = sum_ch Gtile[ch,p]*Ft[ch,p+off_k]
//   (aff v3: windowed b128, kq wave-split, butterfly over cg).
// LDS phase-aliased: Ms | {Gs[64][68] + L[2][9*8*72]}  (union 64 KB).
// ---------------------------------------------------------------------------
__global__ __launch_bounds__(256, 2) void gemm_aff(
    const float* __restrict__ Mt, const float* __restrict__ rw,
    const float* __restrict__ FtE, const float* __restrict__ Ftg,
    float* __restrict__ part)
{
    __shared__ float SH[16384];   // 64 KB
    const int h = blockIdx.x, b = blockIdx.y, cseg = blockIdx.z;
    const int tid = threadIdx.x;

    float* Gs = SH;               // [64][68] = 4352 floats (phase B)
    float* L0 = SH + 4352;        // [2][5184] = 10368 floats (phase B)

    // ======================= phase A: G-tile =======================
    {
        float* Ms = SH;           // [256][64] = 16384 floats (all of SH)
        const int tn = tid & 15, tm = tid >> 4;
        const int m0 = cseg * 64;
        const float* X = FtE + (size_t)b * 1048576 + h * 64 + tn * 4;  // + k*4096

        #pragma unroll
        for (int i = 0; i < 16; ++i) {
            int f = i * 256 + tid;
            int k = f >> 4, mi = f & 15;
            *(f4*)&Ms[k * 64 + mi * 4] = *(const f4*)&Mt[(size_t)k * 256 + m0 + mi * 4];
        }
        __syncthreads();

        f4 acc0 = {0.f,0.f,0.f,0.f}, acc1 = acc0, acc2 = acc0, acc3 = acc0;
        for (int kc = 0; kc < 256; kc += 8) {
            f4 x0 = *(const f4*)(X + (size_t)(kc + 0) * 4096);
            f4 x1 = *(const f4*)(X + (size_t)(kc + 1) * 4096);
            f4 x2 = *(const f4*)(X + (size_t)(kc + 2) * 4096);
            f4 x3 = *(const f4*)(X + (size_t)(kc + 3) * 4096);
            f4 x4 = *(const f4*)(X + (size_t)(kc + 4) * 4096);
            f4 x5 = *(const f4*)(X + (size_t)(kc + 5) * 4096);
            f4 x6 = *(const f4*)(X + (size_t)(kc + 6) * 4096);
            f4 x7 = *(const f4*)(X + (size_t)(kc + 7) * 4096);
            f4 a0 = *(const f4*)&Ms[(kc + 0) * 64 + tm * 4];
            f4 a1 = *(const f4*)&Ms[(kc + 1) * 64 + tm * 4];
            f4 a2 = *(const f4*)&Ms[(kc + 2) * 64 + tm * 4];
            f4 a3 = *(const f4*)&Ms[(kc + 3) * 64 + tm * 4];
            f4 a4 = *(const f4*)&Ms[(kc + 4) * 64 + tm * 4];
            f4 a5 = *(const f4*)&Ms[(kc + 5) * 64 + tm * 4];
            f4 a6 = *(const f4*)&Ms[(kc + 6) * 64 + tm * 4];
            f4 a7 = *(const f4*)&Ms[(kc + 7) * 64 + tm * 4];
            acc0 += x0 * a0.x; acc1 += x0 * a0.y; acc2 += x0 * a0.z; acc3 += x0 * a0.w;
            acc0 += x1 * a1.x; acc1 += x1 * a1.y; acc2 += x1 * a1.z; acc3 += x1 * a1.w;
            acc0 += x2 * a2.x; acc1 += x2 * a2.y; acc2 += x2 * a2.z; acc3 += x2 * a2.w;
            acc0 += x3 * a3.x; acc1 += x3 * a3.y; acc2 += x3 * a3.z; acc3 += x3 * a3.w;
            acc0 += x4 * a4.x; acc1 += x4 * a4.y; acc2 += x4 * a4.z; acc3 += x4 * a4.w;
            acc0 += x5 * a5.x; acc1 += x5 * a5.y; acc2 += x5 * a5.z; acc3 += x5 * a5.w;
            acc0 += x6 * a6.x; acc1 += x6 * a6.y; acc2 += x6 * a6.z; acc3 += x6 * a6.w;
            acc0 += x7 * a7.x; acc1 += x7 * a7.y; acc2 += x7 * a7.z; acc3 += x7 * a7.w;
        }
        __syncthreads();   // all Ms reads complete before Gs/L overwrite

        const int m0g = m0 + tm * 4;
        f4 v;
        v = acc0 + rw[m0g + 0]; *(f4*)&Gs[(tm * 4 + 0) * 68 + tn * 4] = v;
        v = acc1 + rw[m0g + 1]; *(f4*)&Gs[(tm * 4 + 1) * 68 + tn * 4] = v;
        v = acc2 + rw[m0g + 2]; *(f4*)&Gs[(tm * 4 + 2) * 68 + tn * 4] = v;
        v = acc3 + rw[m0g + 3]; *(f4*)&Gs[(tm * 4 + 3) * 68 + tn * 4] = v;
        // visibility of Gs: first __syncthreads() in the phase-B loop.
    }

    // ======================= phase B: aff =======================
    const int wq = tid & 15, cg = (tid >> 4) & 3, kq = tid >> 6;  // kq wave-uniform
    const float* FtB = Ftg + (size_t)b * 1048576;
    const int cbase = cseg * 64;

    int hr[9];
    #pragma unroll
    for (int d = 0; d < 9; ++d) hr[d] = iclamp(h + d - 4, 0, 63);

    f4 vreg[5]; float sreg[3];

    auto load_rnd = [&](int rr) {
        const int c0 = cbase + rr * 8;
        #pragma unroll
        for (int i = 0; i < 5; ++i) {
            int f = i * 256 + tid;
            if (f < 1152) {
                int d = f >> 7, rem = f & 127, ch = rem >> 4, c4 = rem & 15;
                vreg[i] = *(const f4*)&FtB[(size_t)(c0 + ch) * 4096 + hr[d] * 64 + c4 * 4];
            }
        }
        #pragma unroll
        for (int i = 0; i < 3; ++i) {
            int e = i * 256 + tid;
            if (e < 576) {
                int row = e >> 3, sc = e & 7, d = row >> 3, ch = row & 7;
                int wsrc = (sc < 4) ? 0 : 63;
                sreg[i] = FtB[(size_t)(c0 + ch) * 4096 + hr[d] * 64 + wsrc];
            }
        }
    };
    auto store_rnd = [&](int buf) {
        float* Lb = L0 + buf * 5184;
        #pragma unroll
        for (int i = 0; i < 5; ++i) {
            int f = i * 256 + tid;
            if (f < 1152) {
                int d = f >> 7, rem = f & 127, ch = rem >> 4, c4 = rem & 15;
                *(f4*)&Lb[(d * 8 + ch) * 72 + 4 + c4 * 4] = vreg[i];
            }
        }
        #pragma unroll
        for (int i = 0; i < 3; ++i) {
            int e = i * 256 + tid;
            if (e < 576) {
                int row = e >> 3, sc = e & 7, d = row >> 3, ch = row & 7;
                int col = (sc < 4) ? sc : (64 + sc);
                Lb[(d * 8 + ch) * 72 + col] = sreg[i];
            }
        }
    };

    f4 acc[9] = {};

    load_rnd(0); store_rnd(0);
    for (int rr = 0; rr < 8; ++rr) {
        if (rr < 7) load_rnd(rr + 1);
        __syncthreads();
        const float* Lb = L0 + (rr & 1) * 5184;
        const float* egb = Gs + rr * 8 * 68;
        switch (kq) {                      // wave-uniform
            case 0: aff_compute<0>(Lb, egb, wq, cg, acc); break;
            case 1: aff_compute<1>(Lb, egb, wq, cg, acc); break;
            case 2: aff_compute<2>(Lb, egb, wq, cg, acc); break;
            default: aff_compute<3>(Lb, egb, wq, cg, acc); break;
        }
        if (rr < 7) store_rnd((rr + 1) & 1);
    }

    // butterfly-sum the 4 cg channel-pair partials (lane bits 4,5)
    #pragma unroll
    for (int j = 0; j < 9; ++j) {
        acc[j].x += __shfl_xor(acc[j].x, 16); acc[j].x += __shfl_xor(acc[j].x, 32);
        acc[j].y += __shfl_xor(acc[j].y, 16); acc[j].y += __shfl_xor(acc[j].y, 32);
        acc[j].z += __shfl_xor(acc[j].z, 16); acc[j].z += __shfl_xor(acc[j].z, 32);
        acc[j].w += __shfl_xor(acc[j].w, 16); acc[j].w += __shfl_xor(acc[j].w, 32);
    }

    if (cg == 0) {
        float* pB = part + (((size_t)cseg * 2 + b) * 33) * 4096 + h * 64 + wq * 4;
        #define STP(K, J) *(f4*)&pB[(size_t)(K) * 4096] = acc[J];
        switch (kq) {
            case 0: STP(25,0) STP(26,1) STP(27,2) STP(17,3) STP(18,4) STP(19,5) STP(9,6) STP(10,7) STP(11,8) break;
            case 1: STP(1,0) STP(2,1) STP(3,2) STP(4,3) STP(12,4) STP(20,5) STP(28,6) break;
            case 2: STP(0,0) STP(5,1) STP(13,2) STP(21,3) STP(29,4) STP(6,5) STP(7,6) STP(8,7) break;
            default: STP(14,0) STP(15,1) STP(16,2) STP(22,3) STP(23,4) STP(24,5) STP(30,6) STP(31,7) STP(32,8) break;
        }
        #undef STP
    }
}

// ---------------------------------------------------------------------------
// out (fused softmax): per thread, sum 4 cseg partials -> mask -> softmax
// (4-way redundant across cg waves; part L2-resident), then
// out[c][p] = sum_k wgt[k,p]*Ft[c,p+off_k].
// ---------------------------------------------------------------------------
__global__ __launch_bounds__(256, 2) void out_kernel(
    const float* __restrict__ part, const float* __restrict__ Ft,
    float* __restrict__ out)
{
    __shared__ float L[2][9 * 8 * 72];

    const int h = blockIdx.x, b = blockIdx.y, cseg = blockIdx.z;
    const int tid = threadIdx.x;
    const int w = tid & 63, cg = tid >> 6;    // cg wave-uniform
    const size_t plane = (size_t)b * 256 * 4096;
    const float* FtB = Ft + plane;
    float* outB = out + plane;
    const int cbase = cseg * 64;
    const int p = h * 64 + w;

    int hr[9];
    #pragma unroll
    for (int d = 0; d < 9; ++d) hr[d] = iclamp(h + d - 4, 0, 63);

    f4 vreg[5]; float sreg[3];

    auto load_rnd = [&](int rr) {
        const int c0 = cbase + rr * 8;
        #pragma unroll
        for (int i = 0; i < 5; ++i) {
            int f = i * 256 + tid;
            if (f < 1152) {
                int d = f >> 7, rem = f & 127, ch = rem >> 4, c4 = rem & 15;
                vreg[i] = *(const f4*)&FtB[(size_t)(c0 + ch) * 4096 + hr[d] * 64 + c4 * 4];
            }
        }
        #pragma unroll
        for (int i = 0; i < 3; ++i) {
            int e = i * 256 + tid;
            if (e < 576) {
                int row = e >> 3, sc = e & 7, d = row >> 3, ch = row & 7;
                int wsrc = (sc < 4) ? 0 : 63;
                sreg[i] = FtB[(size_t)(c0 + ch) * 4096 + hr[d] * 64 + wsrc];
            }
        }
    };
    auto store_rnd = [&](int buf) {
        float* Lb = L[buf];
        #pragma unroll
        for (int i = 0; i < 5; ++i) {
            int f = i * 256 + tid;
            if (f < 1152) {
                int d = f >> 7, rem = f & 127, ch = rem >> 4, c4 = rem & 15;
                *(f4*)&Lb[(d * 8 + ch) * 72 + 4 + c4 * 4] = vreg[i];
            }
        }
        #pragma unroll
        for (int i = 0; i < 3; ++i) {
            int e = i * 256 + tid;
            if (e < 576) {
                int row = e >> 3, sc = e & 7, d = row >> 3, ch = row & 7;
                int col = (sc < 4) ? sc : (64 + sc);
                Lb[(d * 8 + ch) * 72 + col] = sreg[i];
            }
        }
    };

    load_rnd(0);

    // ---- per-pixel softmax over k ----
    float wv[33];
    {
        constexpr size_t CS = (size_t)2 * 33 * 4096;   // cseg stride in part
        const float* pB = part + ((size_t)b * 33) * 4096 + p;
        float mx = -INFINITY;
        #pragma unroll
        for (int k = 0; k < 33; ++k) {
            size_t off = (size_t)k * 4096;
            float s = pB[off] + pB[CS + off] + pB[2 * CS + off] + pB[3 * CS + off];
            bool valid = ((unsigned)(h + DXC[k]) < 64u) && ((unsigned)(w + DYC[k]) < 64u);
            wv[k] = valid ? s : -INFINITY;
            mx = fmaxf(mx, wv[k]);
        }
        float ssum = 0.f;
        #pragma unroll
        for (int k = 0; k < 33; ++k) { float e = __expf(wv[k] - mx); wv[k] = e; ssum += e; }
        float inv = 1.0f / ssum;
        #pragma unroll
        for (int k = 0; k < 33; ++k) wv[k] *= inv;
    }

    store_rnd(0);
    for (int rr = 0; rr < 8; ++rr) {
        if (rr < 7) load_rnd(rr + 1);
        __syncthreads();
        const float* base = &L[rr & 1][4 + w];
        #pragma unroll
        for (int u = 0; u < 2; ++u) {
            const float* b2 = base + (cg * 2 + u) * 72;
            float o = 0.f;
            #pragma unroll
            for (int k = 0; k < 33; ++k)
                o += wv[k] * b2[(DXC[k] + 4) * 576 + DYC[k]];
            int c = cbase + rr * 8 + cg * 2 + u;
            outB[(size_t)c * 4096 + p] = o;
        }
        if (rr < 7) store_rnd((rr + 1) & 1);
    }
}

// ---------------------------------------------------------------------------
extern "C" void kernel_launch(void* const* d_in, const int* in_sizes, int n_in,
                              void* d_out, int out_size, void* d_ws, size_t ws_size,
                              hipStream_t stream) {
    const float* Ft  = (const float*)d_in[0];
    const float* FtE = (const float*)d_in[1];
    const float* Wf  = (const float*)d_in[2];
    const float* bf  = (const float*)d_in[3];
    const float* Wg  = (const float*)d_in[4];
    const float* bg  = (const float*)d_in[5];
    float* out = (float*)d_out;
    (void)bf;   // bf contributes only a k-constant -> cancelled by softmax

    // ws: part 4.3MB | Mt 256KB | r 1KB   (G eliminated by fusion)
    float* part = (float*)d_ws;                      // [4 cseg][2 b][33][4096]
    float* Mt   = part + (size_t)4 * 2 * 33 * 4096;  // [256 k][256 m] (transposed)
    float* rw   = Mt + 256 * 256;                    // [256]

    hipLaunchKernelGGL(mat_M,      dim3(8, 8),     dim3(256), 0, stream, Wf, Wg, bg, Mt, rw);
    hipLaunchKernelGGL(gemm_aff,   dim3(64, 2, 4), dim3(256), 0, stream, Mt, rw, FtE, Ft, part);
    hipLaunchKernelGGL(out_kernel, dim3(64, 2, 4), dim3(256), 0, stream, part, Ft, out);
}